// Round 14
// baseline (672.611 us; speedup 1.0000x reference)
//
#include <hip/hip_runtime.h>
#include <cstdint>

#define B_ 4
#define N_ 8192
#define DIM_ 512
#define H_ 8
#define DH_ 64
#define M_ 256
#define L_ 32
#define INNER_ 512
#define K3_ 1536
#define RESK_ 33

struct __align__(16) ushort8_t { unsigned short u[8]; };
typedef short bf16x8 __attribute__((ext_vector_type(8)));
typedef float f32x4 __attribute__((ext_vector_type(4)));

__device__ __forceinline__ float bf2f(unsigned short u) {
  return __uint_as_float(((unsigned)u) << 16);
}
__device__ __forceinline__ unsigned short f2bf(float f) {
  unsigned x = __float_as_uint(f);
  return (unsigned short)((x + 0x7fffu + ((x >> 16) & 1u)) >> 16);  // RNE
}

// ---------------- fused LayerNorm -> bf16 activations ----------------
__global__ __launch_bounds__(256) void ln_bf16(const float* __restrict__ x,
    const float* __restrict__ w, const float* __restrict__ bb, unsigned short* __restrict__ xnb)
{
  int row = blockIdx.x;
  int tid = threadIdx.x;
  float2 v = reinterpret_cast<const float2*>(x + (size_t)row * DIM_)[tid];
  float s = v.x + v.y, s2 = v.x * v.x + v.y * v.y;
  #pragma unroll
  for (int off = 32; off; off >>= 1) { s += __shfl_down(s, off); s2 += __shfl_down(s2, off); }
  __shared__ float rs[4], rs2[4];
  int wid = tid >> 6, lane = tid & 63;
  if (lane == 0) { rs[wid] = s; rs2[wid] = s2; }
  __syncthreads();
  float ts = rs[0] + rs[1] + rs[2] + rs[3];
  float ts2 = rs2[0] + rs2[1] + rs2[2] + rs2[3];
  float mu = ts * (1.f / DIM_);
  float var = ts2 * (1.f / DIM_) - mu * mu;
  float inv = rsqrtf(var + 1e-5f);
  int c = tid * 2;
  unsigned int p0 = f2bf((v.x - mu) * inv * w[c] + bb[c]);
  unsigned int p1 = f2bf((v.y - mu) * inv * w[c + 1] + bb[c + 1]);
  reinterpret_cast<unsigned int*>(xnb + (size_t)row * DIM_)[tid] = p0 | (p1 << 16);
}

// ---------------- transpose weights to bf16 ----------------
__global__ __launch_bounds__(256) void transpose_w(const float* __restrict__ src,
    unsigned short* __restrict__ dst, int K, int C, int qcols, float qs)
{
  __shared__ float T[64][65];
  int c0 = blockIdx.x * 64, k0 = blockIdx.y * 64;
  #pragma unroll 4
  for (int it = 0; it < 16; it++) {
    int idx = it * 256 + threadIdx.x;
    int kk = idx >> 6, cc = idx & 63;
    T[kk][cc] = src[(size_t)(k0 + kk) * C + c0 + cc];
  }
  __syncthreads();
  #pragma unroll 4
  for (int it = 0; it < 16; it++) {
    int idx = it * 256 + threadIdx.x;
    int cc = idx >> 6, kk = idx & 63;
    float v = T[kk][cc];
    int c = c0 + cc;
    dst[(size_t)c * K + k0 + kk] = f2bf(c < qcols ? v * qs : v);
  }
}

// ---------------- MFMA GEMM: qkv = xnb @ wT^T, XCD-swizzled, head-major bf16 out ----------------
__global__ __launch_bounds__(256, 2) void mfma_qkv(const unsigned short* __restrict__ xnb,
    const unsigned short* __restrict__ wT,
    unsigned short* __restrict__ qb, unsigned short* __restrict__ kb, unsigned short* __restrict__ vb)
{
  __shared__ unsigned short As[128][72];
  __shared__ unsigned short Bs[128][72];
  int tid = threadIdx.x;
  int nwgx = gridDim.x, nwg = nwgx * gridDim.y;
  int l = blockIdx.y * nwgx + blockIdx.x;
  int swz = (l & 7) * (nwg >> 3) + (l >> 3);
  int bn = (swz % nwgx) * 128, bm = (swz / nwgx) * 128;
  int wid = tid >> 6, lane = tid & 63;
  int wr = wid >> 1, wc = wid & 1;
  int lr = lane & 15, lg = lane >> 4;
  const f32x4 zf = {0.f, 0.f, 0.f, 0.f};
  f32x4 acc[4][4];
  #pragma unroll
  for (int mt = 0; mt < 4; mt++)
    #pragma unroll
    for (int nt = 0; nt < 4; nt++) acc[mt][nt] = zf;

  for (int k0 = 0; k0 < DIM_; k0 += 64) {
    __syncthreads();
    #pragma unroll
    for (int rnd = 0; rnd < 4; rnd++) {
      int idx = rnd * 2048 + tid * 8;
      int row = idx >> 6, col = idx & 63;
      *reinterpret_cast<bf16x8*>(&As[row][col]) =
          *reinterpret_cast<const bf16x8*>(&xnb[(size_t)(bm + row) * DIM_ + k0 + col]);
      *reinterpret_cast<bf16x8*>(&Bs[row][col]) =
          *reinterpret_cast<const bf16x8*>(&wT[(size_t)(bn + row) * DIM_ + k0 + col]);
    }
    __syncthreads();
    bf16x8 af[4][2], bfr[4][2];
    #pragma unroll
    for (int mt = 0; mt < 4; mt++) {
      af[mt][0] = *reinterpret_cast<const bf16x8*>(&As[wr * 64 + mt * 16 + lr][lg * 8]);
      af[mt][1] = *reinterpret_cast<const bf16x8*>(&As[wr * 64 + mt * 16 + lr][32 + lg * 8]);
    }
    #pragma unroll
    for (int nt = 0; nt < 4; nt++) {
      bfr[nt][0] = *reinterpret_cast<const bf16x8*>(&Bs[wc * 64 + nt * 16 + lr][lg * 8]);
      bfr[nt][1] = *reinterpret_cast<const bf16x8*>(&Bs[wc * 64 + nt * 16 + lr][32 + lg * 8]);
    }
    __builtin_amdgcn_s_setprio(1);
    #pragma unroll
    for (int mt = 0; mt < 4; mt++)
      #pragma unroll
      for (int nt = 0; nt < 4; nt++) {
        acc[mt][nt] = __builtin_amdgcn_mfma_f32_16x16x32_bf16(af[mt][0], bfr[nt][0], acc[mt][nt], 0, 0, 0);
        acc[mt][nt] = __builtin_amdgcn_mfma_f32_16x16x32_bf16(af[mt][1], bfr[nt][1], acc[mt][nt], 0, 0, 0);
      }
    __builtin_amdgcn_s_setprio(0);
  }
  #pragma unroll
  for (int nt = 0; nt < 4; nt++) {
    int c = bn + wc * 64 + nt * 16 + lr;
    int which = c >> 9;
    int h = (c >> 6) & (H_ - 1);
    int d = c & 63;
    unsigned short* dst = which == 0 ? qb : (which == 1 ? kb : vb);
    #pragma unroll
    for (int mt = 0; mt < 4; mt++)
      #pragma unroll
      for (int r = 0; r < 4; r++) {
        int row = bm + wr * 64 + mt * 16 + 4 * lg + r;
        int b = row >> 13, n = row & (N_ - 1);
        dst[(((size_t)(b * H_ + h) * N_ + n) << 6) + d] = f2bf(acc[mt][nt][r]);
      }
  }
}

// ---------------- MFMA GEMM: out = oh @ woutT^T + bias + resid (f32 out), XCD-swizzled ----------------
__global__ __launch_bounds__(256, 2) void mfma_out(const unsigned short* __restrict__ oh,
    const unsigned short* __restrict__ wT, const float* __restrict__ bias,
    const float* __restrict__ resid, float* __restrict__ out)
{
  __shared__ unsigned short As[128][72];
  __shared__ unsigned short Bs[128][72];
  int tid = threadIdx.x;
  int nwgx = gridDim.x, nwg = nwgx * gridDim.y;
  int l = blockIdx.y * nwgx + blockIdx.x;
  int swz = (l & 7) * (nwg >> 3) + (l >> 3);
  int bn = (swz % nwgx) * 128, bm = (swz / nwgx) * 128;
  int wid = tid >> 6, lane = tid & 63;
  int wr = wid >> 1, wc = wid & 1;
  int lr = lane & 15, lg = lane >> 4;
  const f32x4 zf = {0.f, 0.f, 0.f, 0.f};
  f32x4 acc[4][4];
  #pragma unroll
  for (int mt = 0; mt < 4; mt++)
    #pragma unroll
    for (int nt = 0; nt < 4; nt++) acc[mt][nt] = zf;

  for (int k0 = 0; k0 < INNER_; k0 += 64) {
    __syncthreads();
    #pragma unroll
    for (int rnd = 0; rnd < 4; rnd++) {
      int idx = rnd * 2048 + tid * 8;
      int row = idx >> 6, col = idx & 63;
      *reinterpret_cast<bf16x8*>(&As[row][col]) =
          *reinterpret_cast<const bf16x8*>(&oh[((size_t)(bm + row) << 9) + k0 + col]);
      *reinterpret_cast<bf16x8*>(&Bs[row][col]) =
          *reinterpret_cast<const bf16x8*>(&wT[(size_t)(bn + row) * INNER_ + k0 + col]);
    }
    __syncthreads();
    bf16x8 af[4][2], bfr[4][2];
    #pragma unroll
    for (int mt = 0; mt < 4; mt++) {
      af[mt][0] = *reinterpret_cast<const bf16x8*>(&As[wr * 64 + mt * 16 + lr][lg * 8]);
      af[mt][1] = *reinterpret_cast<const bf16x8*>(&As[wr * 64 + mt * 16 + lr][32 + lg * 8]);
    }
    #pragma unroll
    for (int nt = 0; nt < 4; nt++) {
      bfr[nt][0] = *reinterpret_cast<const bf16x8*>(&Bs[wc * 64 + nt * 16 + lr][lg * 8]);
      bfr[nt][1] = *reinterpret_cast<const bf16x8*>(&Bs[wc * 64 + nt * 16 + lr][32 + lg * 8]);
    }
    __builtin_amdgcn_s_setprio(1);
    #pragma unroll
    for (int mt = 0; mt < 4; mt++)
      #pragma unroll
      for (int nt = 0; nt < 4; nt++) {
        acc[mt][nt] = __builtin_amdgcn_mfma_f32_16x16x32_bf16(af[mt][0], bfr[nt][0], acc[mt][nt], 0, 0, 0);
        acc[mt][nt] = __builtin_amdgcn_mfma_f32_16x16x32_bf16(af[mt][1], bfr[nt][1], acc[mt][nt], 0, 0, 0);
      }
    __builtin_amdgcn_s_setprio(0);
  }
  #pragma unroll
  for (int nt = 0; nt < 4; nt++) {
    int c = bn + wc * 64 + nt * 16 + lr;
    float bias_c = bias[c];
    #pragma unroll
    for (int mt = 0; mt < 4; mt++)
      #pragma unroll
      for (int r = 0; r < 4; r++) {
        int row = bm + wr * 64 + mt * 16 + 4 * lg + r;
        out[(size_t)row * DIM_ + c] = acc[mt][nt][r] + bias_c + resid[(size_t)row * DIM_ + c];
      }
  }
}

// ---------------- landmark means (f32 + bf16 q_l, bf16 k_l) ----------------
__global__ __launch_bounds__(64) void landmark_kernel(const unsigned short* __restrict__ qb,
    const unsigned short* __restrict__ kb, float* __restrict__ ql, float* __restrict__ kl,
    unsigned short* __restrict__ qlb, unsigned short* __restrict__ klb)
{
  int id = blockIdx.x;
  int m = id & (M_ - 1);
  int bh = id >> 8;
  int d = threadIdx.x;
  size_t base = (((size_t)bh * N_ + m * L_) << 6) + d;
  float sq = 0, sk = 0;
  #pragma unroll 4
  for (int j = 0; j < L_; j++) {
    sq += bf2f(qb[base + ((size_t)j << 6)]);
    sk += bf2f(kb[base + ((size_t)j << 6)]);
  }
  float qv = sq * (1.f / L_);
  float kv = sk * (1.f / L_);
  size_t o = ((size_t)bh * M_ + m) * DH_ + d;
  ql[o] = qv;
  kl[o] = kv;
  qlb[o] = f2bf(qv);
  klb[o] = f2bf(kv);
}

// ---------------- sim2 + softmax -> attn2 (f32 + bf16) ----------------
__global__ __launch_bounds__(256) void attn2_kernel(const float* __restrict__ ql,
    const float* __restrict__ kl, float* __restrict__ a2, unsigned short* __restrict__ a2b)
{
  int id = blockIdx.x;
  int i = id & (M_ - 1);
  int bh = id >> 8;
  int j = threadIdx.x;
  __shared__ float qs[DH_];
  __shared__ float wred[4];
  if (j < DH_) qs[j] = ql[((size_t)bh * M_ + i) * DH_ + j];
  __syncthreads();
  const float* krow = kl + ((size_t)bh * M_ + j) * DH_;
  float s = 0;
  #pragma unroll
  for (int d = 0; d < DH_; d++) s += qs[d] * krow[d];
  float mx = s;
  #pragma unroll
  for (int off = 1; off < 64; off <<= 1) mx = fmaxf(mx, __shfl_xor(mx, off));
  int wid = j >> 6, lane = j & 63;
  if (lane == 0) wred[wid] = mx;
  __syncthreads();
  mx = fmaxf(fmaxf(wred[0], wred[1]), fmaxf(wred[2], wred[3]));
  float e = __expf(s - mx);
  float sum = e;
  #pragma unroll
  for (int off = 1; off < 64; off <<= 1) sum += __shfl_xor(sum, off);
  __syncthreads();
  if (lane == 0) wred[wid] = sum;
  __syncthreads();
  sum = wred[0] + wred[1] + wred[2] + wred[3];
  float p = e / sum;
  size_t o = ((size_t)bh * M_ + i) * M_ + j;
  a2[o] = p;
  a2b[o] = f2bf(p);
}

// ---------------- pinv scale ----------------
__global__ void zero_scal(unsigned int* scal) { scal[threadIdx.x] = 0u; }

__global__ __launch_bounds__(256) void pinv_scale_kernel(const float* __restrict__ a2,
    unsigned int* __restrict__ scal)
{
  int bh = blockIdx.x;
  int t = threadIdx.x;
  const float* xb = a2 + (size_t)bh * M_ * M_;
  float rowsum = 0, colsum = 0;
  for (int j = 0; j < M_; j++) {
    rowsum += xb[(size_t)t * M_ + j];
    colsum += xb[(size_t)j * M_ + t];
  }
  #pragma unroll
  for (int off = 1; off < 64; off <<= 1) {
    rowsum = fmaxf(rowsum, __shfl_xor(rowsum, off));
    colsum = fmaxf(colsum, __shfl_xor(colsum, off));
  }
  __shared__ float wr[4], wc[4];
  int wid = t >> 6, lane = t & 63;
  if (lane == 0) { wr[wid] = rowsum; wc[wid] = colsum; }
  __syncthreads();
  if (t == 0) {
    float rm = fmaxf(fmaxf(wr[0], wr[1]), fmaxf(wr[2], wr[3]));
    float cm = fmaxf(fmaxf(wc[0], wc[1]), fmaxf(wc[2], wc[3]));
    atomicMax(&scal[0], __float_as_uint(rm));
    atomicMax(&scal[1], __float_as_uint(cm));
  }
}

// ---------------- z0 = a2^T/s: row-form (LDS transpose) + T-form (direct) bf16 ----------------
__global__ __launch_bounds__(256) void zinit_kernel(const float* __restrict__ a2,
    const unsigned int* __restrict__ scal,
    unsigned short* __restrict__ zR, unsigned short* __restrict__ zT)
{
  __shared__ float T[64][65];
  int j0 = blockIdx.x * 64, i0 = blockIdx.y * 64;
  size_t bb = (size_t)blockIdx.z * (M_ * M_);
  float inv = 1.f / (__uint_as_float(scal[0]) * __uint_as_float(scal[1]));
  int tid = threadIdx.x;
  #pragma unroll 4
  for (int pass = 0; pass < 16; pass++) {
    int idx = pass * 256 + tid;
    int ii = idx >> 6, jj = idx & 63;
    float v = a2[bb + (size_t)(i0 + ii) * M_ + j0 + jj];
    T[ii][jj] = v;
    zT[bb + (size_t)(i0 + ii) * M_ + j0 + jj] = f2bf(v * inv);
  }
  __syncthreads();
  #pragma unroll 4
  for (int pass = 0; pass < 16; pass++) {
    int idx = pass * 256 + tid;
    int jj = idx >> 6, ii = idx & 63;
    zR[bb + (size_t)(j0 + jj) * M_ + i0 + ii] = f2bf(T[ii][jj] * inv);
  }
}

// ---------------- batched bf16 MFMA GEMM, direct-fragment (no LDS staging, no k-loop barriers) ----------------
// A row-major [m][k]; B T-form [n][k]. Outputs: R (row) = sR*C ; YT (T-form via LDS bounce).
__global__ __launch_bounds__(256, 2) void bgemm_ns(
    const unsigned short* __restrict__ Ab, const unsigned short* __restrict__ BTb,
    unsigned short* __restrict__ Rb, unsigned short* __restrict__ YTb,
    float aY, float sY, float sR)
{
  __shared__ unsigned short Tb[64][72];   // epilogue bounce only
  int bn = blockIdx.x * 64, bm = blockIdx.y * 64;
  size_t bb = (size_t)blockIdx.z * (M_ * M_);
  int tid = threadIdx.x, wid = tid >> 6, lane = tid & 63;
  int lr = lane & 15, lg = lane >> 4;
  int wr = (wid >> 1) * 32, wc = (wid & 1) * 32;
  const f32x4 zf = {0.f, 0.f, 0.f, 0.f};
  f32x4 acc[2][2];
  #pragma unroll
  for (int mt = 0; mt < 2; mt++)
    #pragma unroll
    for (int nt = 0; nt < 2; nt++) acc[mt][nt] = zf;

  const unsigned short* A0 = Ab + bb + (size_t)(bm + wr + lr) * M_ + lg * 8;
  const unsigned short* A1 = A0 + 16 * M_;
  const unsigned short* B0 = BTb + bb + (size_t)(bn + wc + lr) * M_ + lg * 8;
  const unsigned short* B1 = B0 + 16 * M_;
  #pragma unroll
  for (int kk = 0; kk < M_; kk += 32) {
    bf16x8 a0 = *reinterpret_cast<const bf16x8*>(&A0[kk]);
    bf16x8 a1 = *reinterpret_cast<const bf16x8*>(&A1[kk]);
    bf16x8 b0 = *reinterpret_cast<const bf16x8*>(&B0[kk]);
    bf16x8 b1 = *reinterpret_cast<const bf16x8*>(&B1[kk]);
    acc[0][0] = __builtin_amdgcn_mfma_f32_16x16x32_bf16(a0, b0, acc[0][0], 0, 0, 0);
    acc[0][1] = __builtin_amdgcn_mfma_f32_16x16x32_bf16(a0, b1, acc[0][1], 0, 0, 0);
    acc[1][0] = __builtin_amdgcn_mfma_f32_16x16x32_bf16(a1, b0, acc[1][0], 0, 0, 0);
    acc[1][1] = __builtin_amdgcn_mfma_f32_16x16x32_bf16(a1, b1, acc[1][1], 0, 0, 0);
  }
  if (Rb) {
    #pragma unroll
    for (int mt = 0; mt < 2; mt++)
      #pragma unroll
      for (int nt = 0; nt < 2; nt++) {
        int col = bn + wc + nt * 16 + lr;
        #pragma unroll
        for (int r = 0; r < 4; r++) {
          int row = bm + wr + mt * 16 + 4 * lg + r;
          Rb[bb + (size_t)row * M_ + col] = f2bf(sR * acc[mt][nt][r]);
        }
      }
  }
  if (YTb) {
    #pragma unroll
    for (int mt = 0; mt < 2; mt++)
      #pragma unroll
      for (int nt = 0; nt < 2; nt++) {
        int nl = wc + nt * 16 + lr;
        #pragma unroll
        for (int r = 0; r < 4; r++) {
          int ml = wr + mt * 16 + 4 * lg + r;
          float t = sY * acc[mt][nt][r] + ((bm + ml) == (bn + nl) ? aY : 0.f);
          Tb[nl][ml] = f2bf(t);
        }
      }
    __syncthreads();
    #pragma unroll
    for (int pass = 0; pass < 2; pass++) {
      int idx = pass * 2048 + tid * 8;
      int nl = idx >> 6, ml = idx & 63;
      *reinterpret_cast<bf16x8*>(&YTb[bb + (size_t)(bn + nl) * M_ + bm + ml]) =
          *reinterpret_cast<const bf16x8*>(&Tb[nl][ml]);
    }
  }
}

// ---------------- merged NS tail, direct-fragment: z' = 0.25 z@y AND u' = 0.25 u@y (+ vT') ----------------
__global__ __launch_bounds__(256, 2) void bgemm_ns2(
    const unsigned short* __restrict__ Az, const unsigned short* __restrict__ Au,
    const unsigned short* __restrict__ BTb,
    unsigned short* __restrict__ Rz, unsigned short* __restrict__ Ru,
    unsigned short* __restrict__ YTb, int split)
{
  __shared__ unsigned short Tb[64][72];
  int ysel = (int)blockIdx.y >= split;
  const unsigned short* Ab = ysel ? Au : Az;
  unsigned short* Rb = ysel ? Ru : Rz;
  unsigned short* Yb = ysel ? YTb : nullptr;
  int bn = blockIdx.x * 64;
  int bm = ((int)blockIdx.y - (ysel ? split : 0)) * 64;
  size_t bb = (size_t)blockIdx.z * (M_ * M_);
  int tid = threadIdx.x, wid = tid >> 6, lane = tid & 63;
  int lr = lane & 15, lg = lane >> 4;
  int wr = (wid >> 1) * 32, wc = (wid & 1) * 32;
  const f32x4 zf = {0.f, 0.f, 0.f, 0.f};
  f32x4 acc[2][2];
  #pragma unroll
  for (int mt = 0; mt < 2; mt++)
    #pragma unroll
    for (int nt = 0; nt < 2; nt++) acc[mt][nt] = zf;

  const unsigned short* A0 = Ab + bb + (size_t)(bm + wr + lr) * M_ + lg * 8;
  const unsigned short* A1 = A0 + 16 * M_;
  const unsigned short* B0 = BTb + bb + (size_t)(bn + wc + lr) * M_ + lg * 8;
  const unsigned short* B1 = B0 + 16 * M_;
  #pragma unroll
  for (int kk = 0; kk < M_; kk += 32) {
    bf16x8 a0 = *reinterpret_cast<const bf16x8*>(&A0[kk]);
    bf16x8 a1 = *reinterpret_cast<const bf16x8*>(&A1[kk]);
    bf16x8 b0 = *reinterpret_cast<const bf16x8*>(&B0[kk]);
    bf16x8 b1 = *reinterpret_cast<const bf16x8*>(&B1[kk]);
    acc[0][0] = __builtin_amdgcn_mfma_f32_16x16x32_bf16(a0, b0, acc[0][0], 0, 0, 0);
    acc[0][1] = __builtin_amdgcn_mfma_f32_16x16x32_bf16(a0, b1, acc[0][1], 0, 0, 0);
    acc[1][0] = __builtin_amdgcn_mfma_f32_16x16x32_bf16(a1, b0, acc[1][0], 0, 0, 0);
    acc[1][1] = __builtin_amdgcn_mfma_f32_16x16x32_bf16(a1, b1, acc[1][1], 0, 0, 0);
  }
  // R = 0.25 * C
  #pragma unroll
  for (int mt = 0; mt < 2; mt++)
    #pragma unroll
    for (int nt = 0; nt < 2; nt++) {
      int col = bn + wc + nt * 16 + lr;
      #pragma unroll
      for (int r = 0; r < 4; r++) {
        int row = bm + wr + mt * 16 + 4 * lg + r;
        Rb[bb + (size_t)row * M_ + col] = f2bf(0.25f * acc[mt][nt][r]);
      }
    }
  // YT = (7I - 0.25 C)^T  (u-half only)
  if (Yb) {
    #pragma unroll
    for (int mt = 0; mt < 2; mt++)
      #pragma unroll
      for (int nt = 0; nt < 2; nt++) {
        int nl = wc + nt * 16 + lr;
        #pragma unroll
        for (int r = 0; r < 4; r++) {
          int ml = wr + mt * 16 + 4 * lg + r;
          float t = -0.25f * acc[mt][nt][r] + ((bm + ml) == (bn + nl) ? 7.f : 0.f);
          Tb[nl][ml] = f2bf(t);
        }
      }
    __syncthreads();
    #pragma unroll
    for (int pass = 0; pass < 2; pass++) {
      int idx = pass * 2048 + tid * 8;
      int nl = idx >> 6, ml = idx & 63;
      *reinterpret_cast<bf16x8*>(&Yb[bb + (size_t)(bn + nl) * M_ + bm + ml]) =
          *reinterpret_cast<const bf16x8*>(&Tb[nl][ml]);
    }
  }
}

// ---------------- W2 = pinv @ pv -> w2t bf16 [bh][64][256] ----------------
__global__ __launch_bounds__(256) void gemm_w2(
    const unsigned short* __restrict__ zR,
    const unsigned short* __restrict__ pvT, unsigned short* __restrict__ w2t)
{
  int bm = blockIdx.x * 64;
  int batch = blockIdx.y;
  size_t bz = (size_t)batch * (M_ * M_);
  size_t bp = (size_t)batch << 14;
  int tid = threadIdx.x, wid = tid >> 6, lane = tid & 63;
  int lr = lane & 15, lg = lane >> 4;
  int r0 = bm + wid * 16;
  const f32x4 zf = {0.f, 0.f, 0.f, 0.f};
  f32x4 acc[4];
  #pragma unroll
  for (int nt = 0; nt < 4; nt++) acc[nt] = zf;

  #pragma unroll
  for (int k0 = 0; k0 < M_; k0 += 32) {
    bf16x8 a = *reinterpret_cast<const bf16x8*>(&zR[bz + (size_t)(r0 + lr) * M_ + k0 + lg * 8]);
    #pragma unroll
    for (int nt = 0; nt < 4; nt++) {
      bf16x8 b = *reinterpret_cast<const bf16x8*>(&pvT[bp + (size_t)(nt * 16 + lr) * M_ + k0 + lg * 8]);
      acc[nt] = __builtin_amdgcn_mfma_f32_16x16x32_bf16(a, b, acc[nt], 0, 0, 0);
    }
  }
  #pragma unroll
  for (int nt = 0; nt < 4; nt++) {
    int col = nt * 16 + lr;
    #pragma unroll
    for (int r = 0; r < 4; r++) {
      int row = r0 + 4 * lg + r;
      w2t[bp + (size_t)col * M_ + row] = f2bf(acc[nt][r]);
    }
  }
}

// ---------------- pv partials: 8 waves x 32 rows, K/V staged once per (bh,slice) ----------------
__global__ __launch_bounds__(512) void pv_mfma(
    const unsigned short* __restrict__ kb, const unsigned short* __restrict__ vb,
    const unsigned short* __restrict__ qlb,
    float* __restrict__ pvpart, float2* __restrict__ msbuf)
{
  int slice = blockIdx.x;
  int bh    = blockIdx.z;
  int tid = threadIdx.x, wid = tid >> 6, lane = tid & 63;
  int lr = lane & 15, lg = lane >> 4;

  __shared__ unsigned short klds[64][72];
  __shared__ unsigned short vtld[64][72];
  __shared__ unsigned short plds_all[8][32][72];
  unsigned short (*plds)[72] = plds_all[wid];

  int mbase = wid * 32;
  const unsigned short* qbase = qlb + (((size_t)bh * M_ + mbase) << 6);
  bf16x8 qf[2][2];
  #pragma unroll
  for (int rt = 0; rt < 2; rt++)
    #pragma unroll
    for (int h2 = 0; h2 < 2; h2++)
      qf[rt][h2] = *reinterpret_cast<const bf16x8*>(&qbase[((rt * 16 + lr) << 6) + h2 * 32 + lg * 8]);

  const f32x4 zf = {0.f, 0.f, 0.f, 0.f};
  f32x4 oacc[2][4];
  #pragma unroll
  for (int rt = 0; rt < 2; rt++)
    #pragma unroll
    for (int dt = 0; dt < 4; dt++) oacc[rt][dt] = zf;
  float mrun[8], srun[8];
  #pragma unroll
  for (int i = 0; i < 8; i++) { mrun[i] = -1e30f; srun[i] = 0.f; }

  const unsigned short* kgb = kb + (((size_t)bh * N_ + slice * 1024) << 6);
  const unsigned short* vgb = vb + (((size_t)bh * N_ + slice * 1024) << 6);

  for (int c = 0; c < 16; c++) {
    __syncthreads();
    {
      int key = tid >> 3, seg = tid & 7;
      size_t goff = (((size_t)(c * 64 + key)) << 6) + seg * 8;
      bf16x8 kv = *reinterpret_cast<const bf16x8*>(&kgb[goff]);
      *reinterpret_cast<bf16x8*>(&klds[key][seg * 8]) = kv;
      bf16x8 vv = *reinterpret_cast<const bf16x8*>(&vgb[goff]);
      int col = key ^ (seg << 3);
      #pragma unroll
      for (int j = 0; j < 8; j++) vtld[seg * 8 + j][col] = (unsigned short)vv[j];
    }
    __syncthreads();
    f32x4 sacc[2][4];
    #pragma unroll
    for (int rt = 0; rt < 2; rt++)
      #pragma unroll
      for (int ct = 0; ct < 4; ct++) {
        bf16x8 b0 = *reinterpret_cast<const bf16x8*>(&klds[ct * 16 + lr][lg * 8]);
        bf16x8 b1 = *reinterpret_cast<const bf16x8*>(&klds[ct * 16 + lr][32 + lg * 8]);
        f32x4 a = __builtin_amdgcn_mfma_f32_16x16x32_bf16(qf[rt][0], b0, zf, 0, 0, 0);
        sacc[rt][ct] = __builtin_amdgcn_mfma_f32_16x16x32_bf16(qf[rt][1], b1, a, 0, 0, 0);
      }
    #pragma unroll
    for (int rt = 0; rt < 2; rt++)
      #pragma unroll
      for (int r = 0; r < 4; r++) {
        int ri = rt * 4 + r;
        float mc = fmaxf(fmaxf(sacc[rt][0][r], sacc[rt][1][r]), fmaxf(sacc[rt][2][r], sacc[rt][3][r]));
        #pragma unroll
        for (int off = 1; off < 16; off <<= 1) mc = fmaxf(mc, __shfl_xor(mc, off));
        float mnew = fmaxf(mrun[ri], mc);
        float corr = __expf(mrun[ri] - mnew);
        float psum = 0.f;
        #pragma unroll
        for (int ct = 0; ct < 4; ct++) {
          float p = __expf(sacc[rt][ct][r] - mnew);
          sacc[rt][ct][r] = p;
          psum += p;
        }
        #pragma unroll
        for (int off = 1; off < 16; off <<= 1) psum += __shfl_xor(psum, off);
        srun[ri] = srun[ri] * corr + psum;
        mrun[ri] = mnew;
        #pragma unroll
        for (int dt = 0; dt < 4; dt++) oacc[rt][dt][r] *= corr;
        #pragma unroll
        for (int ct = 0; ct < 4; ct++)
          plds[rt * 16 + 4 * lg + r][ct * 16 + lr] = f2bf(sacc[rt][ct][r]);
      }
    __builtin_amdgcn_s_waitcnt(0);
    bf16x8 pa[2][2];
    #pragma unroll
    for (int rt = 0; rt < 2; rt++)
      #pragma unroll
      for (int h = 0; h < 2; h++)
        pa[rt][h] = *reinterpret_cast<const bf16x8*>(&plds[rt * 16 + lr][h * 32 + lg * 8]);
    #pragma unroll
    for (int dt = 0; dt < 4; dt++) {
      int d = dt * 16 + lr;
      bf16x8 bv0 = *reinterpret_cast<const bf16x8*>(&vtld[d][(lg * 8) ^ (d & 0x38)]);
      bf16x8 bv1 = *reinterpret_cast<const bf16x8*>(&vtld[d][(32 + lg * 8) ^ (d & 0x38)]);
      #pragma unroll
      for (int rt = 0; rt < 2; rt++) {
        oacc[rt][dt] = __builtin_amdgcn_mfma_f32_16x16x32_bf16(pa[rt][0], bv0, oacc[rt][dt], 0, 0, 0);
        oacc[rt][dt] = __builtin_amdgcn_mfma_f32_16x16x32_bf16(pa[rt][1], bv1, oacc[rt][dt], 0, 0, 0);
      }
    }
  }
  size_t pbase = (((size_t)(bh * 8 + slice) * M_ + mbase) << 6);
  #pragma unroll
  for (int rt = 0; rt < 2; rt++)
    #pragma unroll
    for (int dt = 0; dt < 4; dt++)
      #pragma unroll
      for (int r = 0; r < 4; r++)
        pvpart[pbase + ((size_t)(rt * 16 + 4 * lg + r) << 6) + dt * 16 + lr] = oacc[rt][dt][r];
  if (lr == 0) {
    #pragma unroll
    for (int rt = 0; rt < 2; rt++)
      #pragma unroll
      for (int r = 0; r < 4; r++)
        msbuf[(size_t)(bh * 8 + slice) * M_ + mbase + rt * 16 + 4 * lg + r] =
            make_float2(mrun[rt * 4 + r], srun[rt * 4 + r]);
  }
}

// ---------------- combine split-N partials -> pv^T bf16 [bh][64][256] ----------------
__global__ __launch_bounds__(256) void pv_combine(const float* __restrict__ pvpart,
    const float2* __restrict__ msbuf, unsigned short* __restrict__ pvT)
{
  int row = blockIdx.x * 4 + (threadIdx.x >> 6);
  int bh = row >> 8, m = row & (M_ - 1);
  int d = threadIdx.x & 63;
  float2 ms[8];
  float mg = -1e30f;
  #pragma unroll
  for (int s = 0; s < 8; s++) {
    ms[s] = msbuf[(size_t)(bh * 8 + s) * M_ + m];
    mg = fmaxf(mg, ms[s].x);
  }
  float ssum = 0.f, o = 0.f;
  #pragma unroll
  for (int s = 0; s < 8; s++) {
    float w = __expf(ms[s].x - mg);
    ssum += ms[s].y * w;
    o += w * pvpart[(((size_t)(bh * 8 + s) * M_ + m) << 6) + d];
  }
  pvT[((size_t)bh << 14) + (size_t)d * M_ + m] = f2bf(o / ssum);
}

// ---------------- attn1: oh = softmax(q @ kl^T) @ W2 via MFMA; kl in LDS, split-m P roundtrip ----------------
__global__ __launch_bounds__(256) void attn1_kernel(
    const unsigned short* __restrict__ qb,
    const unsigned short* __restrict__ klb,
    const unsigned short* __restrict__ w2t,
    unsigned short* __restrict__ oh)
{
  int ntile = blockIdx.x & 31;
  int bh = blockIdx.x >> 5;
  int h = bh & (H_ - 1), b = bh >> 3;
  int tid = threadIdx.x, wid = tid >> 6, lane = tid & 63;
  int lr = lane & 15, lg = lane >> 4;
  __shared__ unsigned short klds[256][68];
  __shared__ unsigned short plds_all[4][16][136];
  unsigned short* plds = &plds_all[wid][0][0];

  const unsigned short* qbh  = qb  + (((size_t)bh * N_) << 6);
  const unsigned short* klbh = klb + ((size_t)bh << 14);
  const unsigned short* w2bh = w2t + ((size_t)bh << 14);

  #pragma unroll
  for (int e = 0; e < 8; e++) {
    int idx = e * 2048 + tid * 8;
    int row = idx >> 6, col = idx & 63;
    *reinterpret_cast<bf16x8*>(&klds[row][col]) =
        *reinterpret_cast<const bf16x8*>(&klbh[((size_t)row << 6) + col]);
  }
  __syncthreads();

  const f32x4 zf = {0.f, 0.f, 0.f, 0.f};
  for (int sub = 0; sub < 4; sub++) {
    int n0 = ntile * 256 + sub * 64 + wid * 16;
    bf16x8 aq0 = *reinterpret_cast<const bf16x8*>(&qbh[((size_t)(n0 + lr) << 6) + lg * 8]);
    bf16x8 aq1 = *reinterpret_cast<const bf16x8*>(&qbh[((size_t)(n0 + lr) << 6) + 32 + lg * 8]);
    f32x4 accs[16];
    __builtin_amdgcn_s_setprio(1);
    #pragma unroll
    for (int mt = 0; mt < 16; mt++) {
      bf16x8 b0 = *reinterpret_cast<const bf16x8*>(&klds[mt * 16 + lr][lg * 8]);
      bf16x8 b1 = *reinterpret_cast<const bf16x8*>(&klds[mt * 16 + lr][32 + lg * 8]);
      f32x4 a = __builtin_amdgcn_mfma_f32_16x16x32_bf16(aq0, b0, zf, 0, 0, 0);
      accs[mt] = __builtin_amdgcn_mfma_f32_16x16x32_bf16(aq1, b1, a, 0, 0, 0);
    }
    __builtin_amdgcn_s_setprio(0);
    float rs[4];
    #pragma unroll
    for (int r = 0; r < 4; r++) {
      float m0 = accs[0][r];
      #pragma unroll
      for (int mt = 1; mt < 16; mt++) m0 = fmaxf(m0, accs[mt][r]);
      #pragma unroll
      for (int off = 1; off < 16; off <<= 1) m0 = fmaxf(m0, __shfl_xor(m0, off));
      float s0 = 0.f;
      #pragma unroll
      for (int mt = 0; mt < 16; mt++) {
        float p = __expf(accs[mt][r] - m0);
        accs[mt][r] = p;
        s0 += p;
      }
      #pragma unroll
      for (int off = 1; off < 16; off <<= 1) s0 += __shfl_xor(s0, off);
      rs[r] = 1.f / s0;
    }
    f32x4 acco[4];
    #pragma unroll
    for (int dt = 0; dt < 4; dt++) acco[dt] = zf;
    #pragma unroll
    for (int half = 0; half < 2; half++) {
      #pragma unroll
      for (int mt = 0; mt < 8; mt++)
        #pragma unroll
        for (int r = 0; r < 4; r++)
          plds[(4 * lg + r) * 136 + mt * 16 + lr] = f2bf(accs[half * 8 + mt][r]);
      __builtin_amdgcn_s_waitcnt(0);
      bf16x8 pa[4];
      #pragma unroll
      for (int mc = 0; mc < 4; mc++)
        pa[mc] = *reinterpret_cast<const bf16x8*>(&plds[lr * 136 + mc * 32 + lg * 8]);
      __builtin_amdgcn_s_setprio(1);
      #pragma unroll
      for (int dt = 0; dt < 4; dt++) {
        #pragma unroll
        for (int mc = 0; mc < 4; mc++) {
          bf16x8 wf = *reinterpret_cast<const bf16x8*>(
              &w2bh[(size_t)(dt * 16 + lr) * M_ + half * 128 + mc * 32 + lg * 8]);
          acco[dt] = __builtin_amdgcn_mfma_f32_16x16x32_bf16(pa[mc], wf, acco[dt], 0, 0, 0);
        }
      }
      __builtin_amdgcn_s_setprio(0);
      __builtin_amdgcn_s_waitcnt(0);
    }
    #pragma unroll
    for (int dt = 0; dt < 4; dt++)
      #pragma unroll
      for (int r = 0; r < 4; r++) {
        int n = n0 + 4 * lg + r;
        oh[((size_t)(b * N_ + n) << 9) + h * DH_ + dt * 16 + lr] = f2bf(acco[dt][r] * rs[r]);
      }
  }
}

// ---------------- depthwise conv residual: register sliding window ----------------
__global__ __launch_bounds__(256) void conv_kernel(const unsigned short* __restrict__ vb,
    const float* __restrict__ rw, unsigned short* __restrict__ oh)
{
  int bh = blockIdx.y;
  int h = bh & (H_ - 1), b = bh >> 3;
  int d = threadIdx.x & 63, g = threadIdx.x >> 6;
  int n0 = blockIdx.x * 128 + g * 32;
  const unsigned short* vbb = vb + (((size_t)bh * N_) << 6) + d;
  float w[64];
  #pragma unroll
  for (int j = 0; j < 64; j++) {
    int nn = n0 - 16 + j;
    w[j] = (nn >= 0 && nn < N_) ? bf2f(vbb[(size_t)nn << 6]) : 0.f;
  }
  float rwr[RESK_];
  #pragma unroll
  for (int j = 0; j < RESK_; j++) rwr[j] = rw[h * RESK_ + j];
  size_t obase = (((size_t)(b * N_ + n0)) << 9) + h * 64 + d;
  #pragma unroll
  for (int t = 0; t < 32; t++) {
    float acc = 0.f;
    #pragma unroll
    for (int j = 0; j < RESK_; j++) acc += rwr[j] * w[t + j];
    size_t oi = obase + ((size_t)t << 9);
    oh[oi] = f2bf(bf2f(oh[oi]) + acc);
  }
}

extern "C" void kernel_launch(void* const* d_in, const int* in_sizes, int n_in,
                              void* d_out, int out_size, void* d_ws, size_t ws_size,
                              hipStream_t stream)
{
  const float* x     = (const float*)d_in[0];
  const float* ln_w  = (const float*)d_in[1];
  const float* ln_b  = (const float*)d_in[2];
  const float* w_qkv = (const float*)d_in[3];
  const float* w_out = (const float*)d_in[4];
  const float* b_out = (const float*)d_in[5];
  const float* res_w = (const float*)d_in[6];
  float* out = (float*)d_out;

  const size_t HEADEL = (size_t)B_ * H_ * N_ * DH_;
  const size_t SMALL  = (size_t)B_ * H_ * M_ * DH_;
  const size_t MSQ    = (size_t)B_ * H_ * M_ * M_;

  char* p = (char*)d_ws;
  auto alloc = [&](size_t bytes) { char* r = p; p += (bytes + 255) & ~(size_t)255; return r; };

  unsigned short* qb  = (unsigned short*)alloc(HEADEL * 2);
  unsigned short* kb  = (unsigned short*)alloc(HEADEL * 2);
  unsigned short* vb  = (unsigned short*)alloc(HEADEL * 2);
  unsigned short* oh  = (unsigned short*)alloc(HEADEL * 2);
  char* unA = alloc(HEADEL * 2);
  unsigned short* xnb = (unsigned short*)unA;
  unsigned short* z0R = (unsigned short*)unA;
  unsigned short* z0T = z0R + MSQ;
  unsigned short* z1R = z0T + MSQ;
  unsigned short* u2  = z1R + MSQ;
  char* unB = alloc(HEADEL * 2);
  float*  pvpart = (float*)unB;
  float2* msbuf  = (float2*)(unB + (size_t)B_ * H_ * 8 * M_ * DH_ * 4);
  unsigned short* ub  = (unsigned short*)unB;
  unsigned short* vTb = ub + MSQ;
  unsigned short* wTb = vTb + MSQ;
  unsigned short* yTb = wTb + MSQ;

  unsigned short* wqkvT = (unsigned short*)alloc((size_t)K3_ * DIM_ * 2);
  unsigned short* woutT = (unsigned short*)alloc((size_t)DIM_ * INNER_ * 2);
  float* ql  = (float*)alloc(SMALL * 4);
  float* kl  = (float*)alloc(SMALL * 4);
  unsigned short* qlb = (unsigned short*)alloc(SMALL * 2);
  unsigned short* klb = (unsigned short*)alloc(SMALL * 2);
  unsigned short* pvT = (unsigned short*)alloc(SMALL * 2);
  unsigned short* w2t = (unsigned short*)alloc(SMALL * 2);
  unsigned short* a2b = (unsigned short*)alloc(MSQ * 2);
  unsigned int* scal  = (unsigned int*)alloc(256);
  if ((size_t)(p - (char*)d_ws) > ws_size) return;

  float* a2 = (float*)d_out;

  ln_bf16<<<B_ * N_, 256, 0, stream>>>(x, ln_w, ln_b, xnb);
  transpose_w<<<dim3(K3_ / 64, DIM_ / 64), 256, 0, stream>>>(w_qkv, wqkvT, DIM_, K3_, INNER_, 0.125f);
  transpose_w<<<dim3(DIM_ / 64, INNER_ / 64), 256, 0, stream>>>(w_out, woutT, INNER_, DIM_, 0, 1.f);
  mfma_qkv<<<dim3(K3_ / 128, (B_ * N_) / 128), 256, 0, stream>>>(xnb, wqkvT, qb, kb, vb);
  landmark_kernel<<<B_ * H_ * M_, 64, 0, stream>>>(qb, kb, ql, kl, qlb, klb);
  attn2_kernel<<<B_ * H_ * M_, 256, 0, stream>>>(ql, kl, a2, a2b);
  zero_scal<<<1, 2, 0, stream>>>(scal);
  pinv_scale_kernel<<<B_ * H_, 256, 0, stream>>>(a2, scal);
  pv_mfma<<<dim3(8, 1, B_ * H_), 512, 0, stream>>>(kb, vb, qlb, pvpart, msbuf);
  pv_combine<<<(B_ * H_ * M_) / 4, 256, 0, stream>>>(pvpart, msbuf, pvT);
  zinit_kernel<<<dim3(4, 4, B_ * H_), 256, 0, stream>>>(a2, scal, z0R, z0T);

  dim3 g44(4, 4, B_ * H_);
  dim3 g48(4, 8, B_ * H_);
  bgemm_ns<<<g44, 256, 0, stream>>>(a2b, z0T, ub, vTb, 7.f, -1.f, 1.f);
  unsigned short *cR = z0R, *nR = z1R, *cu = ub, *nu = u2;
  for (int it = 0; it < 6; it++) {
    bgemm_ns<<<g44, 256, 0, stream>>>(cu, vTb, nullptr, wTb, 15.f, -1.f, 0.f);
    bgemm_ns<<<g44, 256, 0, stream>>>(cu, wTb, nullptr, yTb, 13.f, -1.f, 0.f);
    if (it < 5) {
      bgemm_ns2<<<g48, 256, 0, stream>>>(cR, cu, yTb, nR, nu, vTb, 4);
      unsigned short* t;
      t = cR; cR = nR; nR = t;  t = cu; cu = nu; nu = t;
    } else {
      bgemm_ns2<<<g44, 256, 0, stream>>>(cR, cu, yTb, nR, nu, vTb, 4);
      cR = nR;
    }
  }

  gemm_w2<<<dim3(4, B_ * H_), 256, 0, stream>>>(cR, pvT, w2t);

  attn1_kernel<<<B_ * H_ * (N_ / 256), 256, 0, stream>>>(qb, klb, w2t, oh);
  conv_kernel<<<dim3(N_ / 128, B_ * H_), 256, 0, stream>>>(vb, res_w, oh);
  mfma_out<<<dim3(DIM_ / 128, (B_ * N_) / 128), 256, 0, stream>>>(oh, woutT, b_out, x, out);
}

// Round 15
// 581.599 us; speedup vs baseline: 1.1565x; 1.1565x over previous
//
#include <hip/hip_runtime.h>
#include <cstdint>

#define B_ 4
#define N_ 8192
#define DIM_ 512
#define H_ 8
#define DH_ 64
#define M_ 256
#define L_ 32
#define INNER_ 512
#define K3_ 1536
#define RESK_ 33

struct __align__(16) ushort8_t { unsigned short u[8]; };
typedef short bf16x8 __attribute__((ext_vector_type(8)));
typedef float f32x4 __attribute__((ext_vector_type(4)));

__device__ __forceinline__ float bf2f(unsigned short u) {
  return __uint_as_float(((unsigned)u) << 16);
}
__device__ __forceinline__ unsigned short f2bf(float f) {
  unsigned x = __float_as_uint(f);
  return (unsigned short)((x + 0x7fffu + ((x >> 16) & 1u)) >> 16);  // RNE
}

// ---------------- fused LayerNorm -> bf16 activations ----------------
__global__ __launch_bounds__(256) void ln_bf16(const float* __restrict__ x,
    const float* __restrict__ w, const float* __restrict__ bb, unsigned short* __restrict__ xnb)
{
  int row = blockIdx.x;
  int tid = threadIdx.x;
  float2 v = reinterpret_cast<const float2*>(x + (size_t)row * DIM_)[tid];
  float s = v.x + v.y, s2 = v.x * v.x + v.y * v.y;
  #pragma unroll
  for (int off = 32; off; off >>= 1) { s += __shfl_down(s, off); s2 += __shfl_down(s2, off); }
  __shared__ float rs[4], rs2[4];
  int wid = tid >> 6, lane = tid & 63;
  if (lane == 0) { rs[wid] = s; rs2[wid] = s2; }
  __syncthreads();
  float ts = rs[0] + rs[1] + rs[2] + rs[3];
  float ts2 = rs2[0] + rs2[1] + rs2[2] + rs2[3];
  float mu = ts * (1.f / DIM_);
  float var = ts2 * (1.f / DIM_) - mu * mu;
  float inv = rsqrtf(var + 1e-5f);
  int c = tid * 2;
  unsigned int p0 = f2bf((v.x - mu) * inv * w[c] + bb[c]);
  unsigned int p1 = f2bf((v.y - mu) * inv * w[c + 1] + bb[c + 1]);
  reinterpret_cast<unsigned int*>(xnb + (size_t)row * DIM_)[tid] = p0 | (p1 << 16);
}

// ---------------- transpose weights to bf16 ----------------
__global__ __launch_bounds__(256) void transpose_w(const float* __restrict__ src,
    unsigned short* __restrict__ dst, int K, int C, int qcols, float qs)
{
  __shared__ float T[64][65];
  int c0 = blockIdx.x * 64, k0 = blockIdx.y * 64;
  #pragma unroll 4
  for (int it = 0; it < 16; it++) {
    int idx = it * 256 + threadIdx.x;
    int kk = idx >> 6, cc = idx & 63;
    T[kk][cc] = src[(size_t)(k0 + kk) * C + c0 + cc];
  }
  __syncthreads();
  #pragma unroll 4
  for (int it = 0; it < 16; it++) {
    int idx = it * 256 + threadIdx.x;
    int cc = idx >> 6, kk = idx & 63;
    float v = T[kk][cc];
    int c = c0 + cc;
    dst[(size_t)c * K + k0 + kk] = f2bf(c < qcols ? v * qs : v);
  }
}

// ---------------- MFMA GEMM: qkv = xnb @ wT^T, XCD-swizzled, head-major bf16 out ----------------
__global__ __launch_bounds__(256, 2) void mfma_qkv(const unsigned short* __restrict__ xnb,
    const unsigned short* __restrict__ wT,
    unsigned short* __restrict__ qb, unsigned short* __restrict__ kb, unsigned short* __restrict__ vb)
{
  __shared__ unsigned short As[128][72];
  __shared__ unsigned short Bs[128][72];
  int tid = threadIdx.x;
  int nwgx = gridDim.x, nwg = nwgx * gridDim.y;
  int l = blockIdx.y * nwgx + blockIdx.x;
  int swz = (l & 7) * (nwg >> 3) + (l >> 3);
  int bn = (swz % nwgx) * 128, bm = (swz / nwgx) * 128;
  int wid = tid >> 6, lane = tid & 63;
  int wr = wid >> 1, wc = wid & 1;
  int lr = lane & 15, lg = lane >> 4;
  const f32x4 zf = {0.f, 0.f, 0.f, 0.f};
  f32x4 acc[4][4];
  #pragma unroll
  for (int mt = 0; mt < 4; mt++)
    #pragma unroll
    for (int nt = 0; nt < 4; nt++) acc[mt][nt] = zf;

  for (int k0 = 0; k0 < DIM_; k0 += 64) {
    __syncthreads();
    #pragma unroll
    for (int rnd = 0; rnd < 4; rnd++) {
      int idx = rnd * 2048 + tid * 8;
      int row = idx >> 6, col = idx & 63;
      *reinterpret_cast<bf16x8*>(&As[row][col]) =
          *reinterpret_cast<const bf16x8*>(&xnb[(size_t)(bm + row) * DIM_ + k0 + col]);
      *reinterpret_cast<bf16x8*>(&Bs[row][col]) =
          *reinterpret_cast<const bf16x8*>(&wT[(size_t)(bn + row) * DIM_ + k0 + col]);
    }
    __syncthreads();
    bf16x8 af[4][2], bfr[4][2];
    #pragma unroll
    for (int mt = 0; mt < 4; mt++) {
      af[mt][0] = *reinterpret_cast<const bf16x8*>(&As[wr * 64 + mt * 16 + lr][lg * 8]);
      af[mt][1] = *reinterpret_cast<const bf16x8*>(&As[wr * 64 + mt * 16 + lr][32 + lg * 8]);
    }
    #pragma unroll
    for (int nt = 0; nt < 4; nt++) {
      bfr[nt][0] = *reinterpret_cast<const bf16x8*>(&Bs[wc * 64 + nt * 16 + lr][lg * 8]);
      bfr[nt][1] = *reinterpret_cast<const bf16x8*>(&Bs[wc * 64 + nt * 16 + lr][32 + lg * 8]);
    }
    __builtin_amdgcn_s_setprio(1);
    #pragma unroll
    for (int mt = 0; mt < 4; mt++)
      #pragma unroll
      for (int nt = 0; nt < 4; nt++) {
        acc[mt][nt] = __builtin_amdgcn_mfma_f32_16x16x32_bf16(af[mt][0], bfr[nt][0], acc[mt][nt], 0, 0, 0);
        acc[mt][nt] = __builtin_amdgcn_mfma_f32_16x16x32_bf16(af[mt][1], bfr[nt][1], acc[mt][nt], 0, 0, 0);
      }
    __builtin_amdgcn_s_setprio(0);
  }
  #pragma unroll
  for (int nt = 0; nt < 4; nt++) {
    int c = bn + wc * 64 + nt * 16 + lr;
    int which = c >> 9;
    int h = (c >> 6) & (H_ - 1);
    int d = c & 63;
    unsigned short* dst = which == 0 ? qb : (which == 1 ? kb : vb);
    #pragma unroll
    for (int mt = 0; mt < 4; mt++)
      #pragma unroll
      for (int r = 0; r < 4; r++) {
        int row = bm + wr * 64 + mt * 16 + 4 * lg + r;
        int b = row >> 13, n = row & (N_ - 1);
        dst[(((size_t)(b * H_ + h) * N_ + n) << 6) + d] = f2bf(acc[mt][nt][r]);
      }
  }
}

// ---------------- MFMA GEMM: out = oh @ woutT^T + bias + resid (f32 out), XCD-swizzled ----------------
__global__ __launch_bounds__(256, 2) void mfma_out(const unsigned short* __restrict__ oh,
    const unsigned short* __restrict__ wT, const float* __restrict__ bias,
    const float* __restrict__ resid, float* __restrict__ out)
{
  __shared__ unsigned short As[128][72];
  __shared__ unsigned short Bs[128][72];
  int tid = threadIdx.x;
  int nwgx = gridDim.x, nwg = nwgx * gridDim.y;
  int l = blockIdx.y * nwgx + blockIdx.x;
  int swz = (l & 7) * (nwg >> 3) + (l >> 3);
  int bn = (swz % nwgx) * 128, bm = (swz / nwgx) * 128;
  int wid = tid >> 6, lane = tid & 63;
  int wr = wid >> 1, wc = wid & 1;
  int lr = lane & 15, lg = lane >> 4;
  const f32x4 zf = {0.f, 0.f, 0.f, 0.f};
  f32x4 acc[4][4];
  #pragma unroll
  for (int mt = 0; mt < 4; mt++)
    #pragma unroll
    for (int nt = 0; nt < 4; nt++) acc[mt][nt] = zf;

  for (int k0 = 0; k0 < INNER_; k0 += 64) {
    __syncthreads();
    #pragma unroll
    for (int rnd = 0; rnd < 4; rnd++) {
      int idx = rnd * 2048 + tid * 8;
      int row = idx >> 6, col = idx & 63;
      *reinterpret_cast<bf16x8*>(&As[row][col]) =
          *reinterpret_cast<const bf16x8*>(&oh[((size_t)(bm + row) << 9) + k0 + col]);
      *reinterpret_cast<bf16x8*>(&Bs[row][col]) =
          *reinterpret_cast<const bf16x8*>(&wT[(size_t)(bn + row) * INNER_ + k0 + col]);
    }
    __syncthreads();
    bf16x8 af[4][2], bfr[4][2];
    #pragma unroll
    for (int mt = 0; mt < 4; mt++) {
      af[mt][0] = *reinterpret_cast<const bf16x8*>(&As[wr * 64 + mt * 16 + lr][lg * 8]);
      af[mt][1] = *reinterpret_cast<const bf16x8*>(&As[wr * 64 + mt * 16 + lr][32 + lg * 8]);
    }
    #pragma unroll
    for (int nt = 0; nt < 4; nt++) {
      bfr[nt][0] = *reinterpret_cast<const bf16x8*>(&Bs[wc * 64 + nt * 16 + lr][lg * 8]);
      bfr[nt][1] = *reinterpret_cast<const bf16x8*>(&Bs[wc * 64 + nt * 16 + lr][32 + lg * 8]);
    }
    __builtin_amdgcn_s_setprio(1);
    #pragma unroll
    for (int mt = 0; mt < 4; mt++)
      #pragma unroll
      for (int nt = 0; nt < 4; nt++) {
        acc[mt][nt] = __builtin_amdgcn_mfma_f32_16x16x32_bf16(af[mt][0], bfr[nt][0], acc[mt][nt], 0, 0, 0);
        acc[mt][nt] = __builtin_amdgcn_mfma_f32_16x16x32_bf16(af[mt][1], bfr[nt][1], acc[mt][nt], 0, 0, 0);
      }
    __builtin_amdgcn_s_setprio(0);
  }
  #pragma unroll
  for (int nt = 0; nt < 4; nt++) {
    int c = bn + wc * 64 + nt * 16 + lr;
    float bias_c = bias[c];
    #pragma unroll
    for (int mt = 0; mt < 4; mt++)
      #pragma unroll
      for (int r = 0; r < 4; r++) {
        int row = bm + wr * 64 + mt * 16 + 4 * lg + r;
        out[(size_t)row * DIM_ + c] = acc[mt][nt][r] + bias_c + resid[(size_t)row * DIM_ + c];
      }
  }
}

// ---------------- landmark means (f32 + bf16 q_l, bf16 k_l) ----------------
__global__ __launch_bounds__(64) void landmark_kernel(const unsigned short* __restrict__ qb,
    const unsigned short* __restrict__ kb, float* __restrict__ ql, float* __restrict__ kl,
    unsigned short* __restrict__ qlb, unsigned short* __restrict__ klb)
{
  int id = blockIdx.x;
  int m = id & (M_ - 1);
  int bh = id >> 8;
  int d = threadIdx.x;
  size_t base = (((size_t)bh * N_ + m * L_) << 6) + d;
  float sq = 0, sk = 0;
  #pragma unroll 4
  for (int j = 0; j < L_; j++) {
    sq += bf2f(qb[base + ((size_t)j << 6)]);
    sk += bf2f(kb[base + ((size_t)j << 6)]);
  }
  float qv = sq * (1.f / L_);
  float kv = sk * (1.f / L_);
  size_t o = ((size_t)bh * M_ + m) * DH_ + d;
  ql[o] = qv;
  kl[o] = kv;
  qlb[o] = f2bf(qv);
  klb[o] = f2bf(kv);
}

// ---------------- sim2 + softmax -> attn2 (f32 + bf16) ----------------
__global__ __launch_bounds__(256) void attn2_kernel(const float* __restrict__ ql,
    const float* __restrict__ kl, float* __restrict__ a2, unsigned short* __restrict__ a2b)
{
  int id = blockIdx.x;
  int i = id & (M_ - 1);
  int bh = id >> 8;
  int j = threadIdx.x;
  __shared__ float qs[DH_];
  __shared__ float wred[4];
  if (j < DH_) qs[j] = ql[((size_t)bh * M_ + i) * DH_ + j];
  __syncthreads();
  const float* krow = kl + ((size_t)bh * M_ + j) * DH_;
  float s = 0;
  #pragma unroll
  for (int d = 0; d < DH_; d++) s += qs[d] * krow[d];
  float mx = s;
  #pragma unroll
  for (int off = 1; off < 64; off <<= 1) mx = fmaxf(mx, __shfl_xor(mx, off));
  int wid = j >> 6, lane = j & 63;
  if (lane == 0) wred[wid] = mx;
  __syncthreads();
  mx = fmaxf(fmaxf(wred[0], wred[1]), fmaxf(wred[2], wred[3]));
  float e = __expf(s - mx);
  float sum = e;
  #pragma unroll
  for (int off = 1; off < 64; off <<= 1) sum += __shfl_xor(sum, off);
  __syncthreads();
  if (lane == 0) wred[wid] = sum;
  __syncthreads();
  sum = wred[0] + wred[1] + wred[2] + wred[3];
  float p = e / sum;
  size_t o = ((size_t)bh * M_ + i) * M_ + j;
  a2[o] = p;
  a2b[o] = f2bf(p);
}

// ---------------- pinv scale ----------------
__global__ void zero_scal(unsigned int* scal) { scal[threadIdx.x] = 0u; }

__global__ __launch_bounds__(256) void pinv_scale_kernel(const float* __restrict__ a2,
    unsigned int* __restrict__ scal)
{
  int bh = blockIdx.x;
  int t = threadIdx.x;
  const float* xb = a2 + (size_t)bh * M_ * M_;
  float rowsum = 0, colsum = 0;
  for (int j = 0; j < M_; j++) {
    rowsum += xb[(size_t)t * M_ + j];
    colsum += xb[(size_t)j * M_ + t];
  }
  #pragma unroll
  for (int off = 1; off < 64; off <<= 1) {
    rowsum = fmaxf(rowsum, __shfl_xor(rowsum, off));
    colsum = fmaxf(colsum, __shfl_xor(colsum, off));
  }
  __shared__ float wr[4], wc[4];
  int wid = t >> 6, lane = t & 63;
  if (lane == 0) { wr[wid] = rowsum; wc[wid] = colsum; }
  __syncthreads();
  if (t == 0) {
    float rm = fmaxf(fmaxf(wr[0], wr[1]), fmaxf(wr[2], wr[3]));
    float cm = fmaxf(fmaxf(wc[0], wc[1]), fmaxf(wc[2], wc[3]));
    atomicMax(&scal[0], __float_as_uint(rm));
    atomicMax(&scal[1], __float_as_uint(cm));
  }
}

// ---------------- z0 = a2^T/s: row-form (LDS transpose) + T-form (direct) bf16 ----------------
__global__ __launch_bounds__(256) void zinit_kernel(const float* __restrict__ a2,
    const unsigned int* __restrict__ scal,
    unsigned short* __restrict__ zR, unsigned short* __restrict__ zT)
{
  __shared__ float T[64][65];
  int j0 = blockIdx.x * 64, i0 = blockIdx.y * 64;
  size_t bb = (size_t)blockIdx.z * (M_ * M_);
  float inv = 1.f / (__uint_as_float(scal[0]) * __uint_as_float(scal[1]));
  int tid = threadIdx.x;
  #pragma unroll 4
  for (int pass = 0; pass < 16; pass++) {
    int idx = pass * 256 + tid;
    int ii = idx >> 6, jj = idx & 63;
    float v = a2[bb + (size_t)(i0 + ii) * M_ + j0 + jj];
    T[ii][jj] = v;
    zT[bb + (size_t)(i0 + ii) * M_ + j0 + jj] = f2bf(v * inv);
  }
  __syncthreads();
  #pragma unroll 4
  for (int pass = 0; pass < 16; pass++) {
    int idx = pass * 256 + tid;
    int jj = idx >> 6, ii = idx & 63;
    zR[bb + (size_t)(j0 + jj) * M_ + i0 + ii] = f2bf(T[ii][jj] * inv);
  }
}

// ---------------- batched bf16 MFMA GEMM, LDS-staged, 8 waves x 16x32 tiles ----------------
// A row-major [m][k]; B T-form [n][k]. Outputs: R (row) = sR*C ; YT (T-form via LDS bounce).
__global__ __launch_bounds__(512, 2) void bgemm_ns(
    const unsigned short* __restrict__ Ab, const unsigned short* __restrict__ BTb,
    unsigned short* __restrict__ Rb, unsigned short* __restrict__ YTb,
    float aY, float sY, float sR)
{
  __shared__ unsigned short Ash[64][72];
  __shared__ unsigned short Bsh[64][72];
  int bn = blockIdx.x * 64, bm = blockIdx.y * 64;
  size_t bb = (size_t)blockIdx.z * (M_ * M_);
  int tid = threadIdx.x, wid = tid >> 6, lane = tid & 63;
  int lr = lane & 15, lg = lane >> 4;
  int wr = (wid & 3) * 16, wc = (wid >> 2) * 32;   // wave tile 16x32
  const f32x4 zf = {0.f, 0.f, 0.f, 0.f};
  f32x4 acc[2] = {zf, zf};

  int srow = tid >> 3, scol = (tid & 7) * 8;       // 512 thr: one b128 per array
  for (int k0 = 0; k0 < M_; k0 += 64) {
    __syncthreads();
    *reinterpret_cast<bf16x8*>(&Ash[srow][scol]) =
        *reinterpret_cast<const bf16x8*>(&Ab[bb + (size_t)(bm + srow) * M_ + k0 + scol]);
    *reinterpret_cast<bf16x8*>(&Bsh[srow][scol]) =
        *reinterpret_cast<const bf16x8*>(&BTb[bb + (size_t)(bn + srow) * M_ + k0 + scol]);
    __syncthreads();
    #pragma unroll
    for (int kk = 0; kk < 64; kk += 32) {
      bf16x8 a  = *reinterpret_cast<const bf16x8*>(&Ash[wr + lr][kk + lg * 8]);
      bf16x8 b0 = *reinterpret_cast<const bf16x8*>(&Bsh[wc + lr][kk + lg * 8]);
      bf16x8 b1 = *reinterpret_cast<const bf16x8*>(&Bsh[wc + 16 + lr][kk + lg * 8]);
      acc[0] = __builtin_amdgcn_mfma_f32_16x16x32_bf16(a, b0, acc[0], 0, 0, 0);
      acc[1] = __builtin_amdgcn_mfma_f32_16x16x32_bf16(a, b1, acc[1], 0, 0, 0);
    }
  }
  if (Rb) {
    #pragma unroll
    for (int nt = 0; nt < 2; nt++) {
      int col = bn + wc + nt * 16 + lr;
      #pragma unroll
      for (int r = 0; r < 4; r++) {
        int row = bm + wr + 4 * lg + r;
        Rb[bb + (size_t)row * M_ + col] = f2bf(sR * acc[nt][r]);
      }
    }
  }
  if (YTb) {
    __syncthreads();
    #pragma unroll
    for (int nt = 0; nt < 2; nt++) {
      int nl = wc + nt * 16 + lr;
      #pragma unroll
      for (int r = 0; r < 4; r++) {
        int ml = wr + 4 * lg + r;
        float t = sY * acc[nt][r] + ((bm + ml) == (bn + nl) ? aY : 0.f);
        Ash[nl][ml] = f2bf(t);
      }
    }
    __syncthreads();
    *reinterpret_cast<bf16x8*>(&YTb[bb + (size_t)(bn + srow) * M_ + bm + scol]) =
        *reinterpret_cast<const bf16x8*>(&Ash[srow][scol]);
  }
}

// ---------------- merged NS tail: z' = 0.25 z@y AND u' = 0.25 u@y (+ vT'), 8-wave ----------------
__global__ __launch_bounds__(512, 2) void bgemm_ns2(
    const unsigned short* __restrict__ Az, const unsigned short* __restrict__ Au,
    const unsigned short* __restrict__ BTb,
    unsigned short* __restrict__ Rz, unsigned short* __restrict__ Ru,
    unsigned short* __restrict__ YTb, int split)
{
  __shared__ unsigned short Ash[64][72];
  __shared__ unsigned short Bsh[64][72];
  int ysel = (int)blockIdx.y >= split;
  const unsigned short* Ab = ysel ? Au : Az;
  unsigned short* Rb = ysel ? Ru : Rz;
  unsigned short* Yb = ysel ? YTb : nullptr;
  int bn = blockIdx.x * 64;
  int bm = ((int)blockIdx.y - (ysel ? split : 0)) * 64;
  size_t bb = (size_t)blockIdx.z * (M_ * M_);
  int tid = threadIdx.x, wid = tid >> 6, lane = tid & 63;
  int lr = lane & 15, lg = lane >> 4;
  int wr = (wid & 3) * 16, wc = (wid >> 2) * 32;
  const f32x4 zf = {0.f, 0.f, 0.f, 0.f};
  f32x4 acc[2] = {zf, zf};

  int srow = tid >> 3, scol = (tid & 7) * 8;
  for (int k0 = 0; k0 < M_; k0 += 64) {
    __syncthreads();
    *reinterpret_cast<bf16x8*>(&Ash[srow][scol]) =
        *reinterpret_cast<const bf16x8*>(&Ab[bb + (size_t)(bm + srow) * M_ + k0 + scol]);
    *reinterpret_cast<bf16x8*>(&Bsh[srow][scol]) =
        *reinterpret_cast<const bf16x8*>(&BTb[bb + (size_t)(bn + srow) * M_ + k0 + scol]);
    __syncthreads();
    #pragma unroll
    for (int kk = 0; kk < 64; kk += 32) {
      bf16x8 a  = *reinterpret_cast<const bf16x8*>(&Ash[wr + lr][kk + lg * 8]);
      bf16x8 b0 = *reinterpret_cast<const bf16x8*>(&Bsh[wc + lr][kk + lg * 8]);
      bf16x8 b1 = *reinterpret_cast<const bf16x8*>(&Bsh[wc + 16 + lr][kk + lg * 8]);
      acc[0] = __builtin_amdgcn_mfma_f32_16x16x32_bf16(a, b0, acc[0], 0, 0, 0);
      acc[1] = __builtin_amdgcn_mfma_f32_16x16x32_bf16(a, b1, acc[1], 0, 0, 0);
    }
  }
  // R = 0.25 * C
  #pragma unroll
  for (int nt = 0; nt < 2; nt++) {
    int col = bn + wc + nt * 16 + lr;
    #pragma unroll
    for (int r = 0; r < 4; r++) {
      int row = bm + wr + 4 * lg + r;
      Rb[bb + (size_t)row * M_ + col] = f2bf(0.25f * acc[nt][r]);
    }
  }
  // YT = (7I - 0.25 C)^T  (u-half only)
  if (Yb) {
    __syncthreads();
    #pragma unroll
    for (int nt = 0; nt < 2; nt++) {
      int nl = wc + nt * 16 + lr;
      #pragma unroll
      for (int r = 0; r < 4; r++) {
        int ml = wr + 4 * lg + r;
        float t = -0.25f * acc[nt][r] + ((bm + ml) == (bn + nl) ? 7.f : 0.f);
        Ash[nl][ml] = f2bf(t);
      }
    }
    __syncthreads();
    *reinterpret_cast<bf16x8*>(&Yb[bb + (size_t)(bn + srow) * M_ + bm + scol]) =
        *reinterpret_cast<const bf16x8*>(&Ash[srow][scol]);
  }
}

// ---------------- W2 = pinv @ pv -> w2t bf16 [bh][64][256] ----------------
__global__ __launch_bounds__(256) void gemm_w2(
    const unsigned short* __restrict__ zR,
    const unsigned short* __restrict__ pvT, unsigned short* __restrict__ w2t)
{
  int bm = blockIdx.x * 64;
  int batch = blockIdx.y;
  size_t bz = (size_t)batch * (M_ * M_);
  size_t bp = (size_t)batch << 14;
  int tid = threadIdx.x, wid = tid >> 6, lane = tid & 63;
  int lr = lane & 15, lg = lane >> 4;
  int r0 = bm + wid * 16;
  const f32x4 zf = {0.f, 0.f, 0.f, 0.f};
  f32x4 acc[4];
  #pragma unroll
  for (int nt = 0; nt < 4; nt++) acc[nt] = zf;

  #pragma unroll
  for (int k0 = 0; k0 < M_; k0 += 32) {
    bf16x8 a = *reinterpret_cast<const bf16x8*>(&zR[bz + (size_t)(r0 + lr) * M_ + k0 + lg * 8]);
    #pragma unroll
    for (int nt = 0; nt < 4; nt++) {
      bf16x8 b = *reinterpret_cast<const bf16x8*>(&pvT[bp + (size_t)(nt * 16 + lr) * M_ + k0 + lg * 8]);
      acc[nt] = __builtin_amdgcn_mfma_f32_16x16x32_bf16(a, b, acc[nt], 0, 0, 0);
    }
  }
  #pragma unroll
  for (int nt = 0; nt < 4; nt++) {
    int col = nt * 16 + lr;
    #pragma unroll
    for (int r = 0; r < 4; r++) {
      int row = r0 + 4 * lg + r;
      w2t[bp + (size_t)col * M_ + row] = f2bf(acc[nt][r]);
    }
  }
}

// ---------------- pv partials: 8 waves x 32 rows, K/V staged once per (bh,slice) ----------------
__global__ __launch_bounds__(512) void pv_mfma(
    const unsigned short* __restrict__ kb, const unsigned short* __restrict__ vb,
    const unsigned short* __restrict__ qlb,
    float* __restrict__ pvpart, float2* __restrict__ msbuf)
{
  int slice = blockIdx.x;
  int bh    = blockIdx.z;
  int tid = threadIdx.x, wid = tid >> 6, lane = tid & 63;
  int lr = lane & 15, lg = lane >> 4;

  __shared__ unsigned short klds[64][72];
  __shared__ unsigned short vtld[64][72];
  __shared__ unsigned short plds_all[8][32][72];
  unsigned short (*plds)[72] = plds_all[wid];

  int mbase = wid * 32;
  const unsigned short* qbase = qlb + (((size_t)bh * M_ + mbase) << 6);
  bf16x8 qf[2][2];
  #pragma unroll
  for (int rt = 0; rt < 2; rt++)
    #pragma unroll
    for (int h2 = 0; h2 < 2; h2++)
      qf[rt][h2] = *reinterpret_cast<const bf16x8*>(&qbase[((rt * 16 + lr) << 6) + h2 * 32 + lg * 8]);

  const f32x4 zf = {0.f, 0.f, 0.f, 0.f};
  f32x4 oacc[2][4];
  #pragma unroll
  for (int rt = 0; rt < 2; rt++)
    #pragma unroll
    for (int dt = 0; dt < 4; dt++) oacc[rt][dt] = zf;
  float mrun[8], srun[8];
  #pragma unroll
  for (int i = 0; i < 8; i++) { mrun[i] = -1e30f; srun[i] = 0.f; }

  const unsigned short* kgb = kb + (((size_t)bh * N_ + slice * 1024) << 6);
  const unsigned short* vgb = vb + (((size_t)bh * N_ + slice * 1024) << 6);

  for (int c = 0; c < 16; c++) {
    __syncthreads();
    {
      int key = tid >> 3, seg = tid & 7;
      size_t goff = (((size_t)(c * 64 + key)) << 6) + seg * 8;
      bf16x8 kv = *reinterpret_cast<const bf16x8*>(&kgb[goff]);
      *reinterpret_cast<bf16x8*>(&klds[key][seg * 8]) = kv;
      bf16x8 vv = *reinterpret_cast<const bf16x8*>(&vgb[goff]);
      int col = key ^ (seg << 3);
      #pragma unroll
      for (int j = 0; j < 8; j++) vtld[seg * 8 + j][col] = (unsigned short)vv[j];
    }
    __syncthreads();
    f32x4 sacc[2][4];
    #pragma unroll
    for (int rt = 0; rt < 2; rt++)
      #pragma unroll
      for (int ct = 0; ct < 4; ct++) {
        bf16x8 b0 = *reinterpret_cast<const bf16x8*>(&klds[ct * 16 + lr][lg * 8]);
        bf16x8 b1 = *reinterpret_cast<const bf16x8*>(&klds[ct * 16 + lr][32 + lg * 8]);
        f32x4 a = __builtin_amdgcn_mfma_f32_16x16x32_bf16(qf[rt][0], b0, zf, 0, 0, 0);
        sacc[rt][ct] = __builtin_amdgcn_mfma_f32_16x16x32_bf16(qf[rt][1], b1, a, 0, 0, 0);
      }
    #pragma unroll
    for (int rt = 0; rt < 2; rt++)
      #pragma unroll
      for (int r = 0; r < 4; r++) {
        int ri = rt * 4 + r;
        float mc = fmaxf(fmaxf(sacc[rt][0][r], sacc[rt][1][r]), fmaxf(sacc[rt][2][r], sacc[rt][3][r]));
        #pragma unroll
        for (int off = 1; off < 16; off <<= 1) mc = fmaxf(mc, __shfl_xor(mc, off));
        float mnew = fmaxf(mrun[ri], mc);
        float corr = __expf(mrun[ri] - mnew);
        float psum = 0.f;
        #pragma unroll
        for (int ct = 0; ct < 4; ct++) {
          float p = __expf(sacc[rt][ct][r] - mnew);
          sacc[rt][ct][r] = p;
          psum += p;
        }
        #pragma unroll
        for (int off = 1; off < 16; off <<= 1) psum += __shfl_xor(psum, off);
        srun[ri] = srun[ri] * corr + psum;
        mrun[ri] = mnew;
        #pragma unroll
        for (int dt = 0; dt < 4; dt++) oacc[rt][dt][r] *= corr;
        #pragma unroll
        for (int ct = 0; ct < 4; ct++)
          plds[rt * 16 + 4 * lg + r][ct * 16 + lr] = f2bf(sacc[rt][ct][r]);
      }
    __builtin_amdgcn_s_waitcnt(0);
    bf16x8 pa[2][2];
    #pragma unroll
    for (int rt = 0; rt < 2; rt++)
      #pragma unroll
      for (int h = 0; h < 2; h++)
        pa[rt][h] = *reinterpret_cast<const bf16x8*>(&plds[rt * 16 + lr][h * 32 + lg * 8]);
    #pragma unroll
    for (int dt = 0; dt < 4; dt++) {
      int d = dt * 16 + lr;
      bf16x8 bv0 = *reinterpret_cast<const bf16x8*>(&vtld[d][(lg * 8) ^ (d & 0x38)]);
      bf16x8 bv1 = *reinterpret_cast<const bf16x8*>(&vtld[d][(32 + lg * 8) ^ (d & 0x38)]);
      #pragma unroll
      for (int rt = 0; rt < 2; rt++) {
        oacc[rt][dt] = __builtin_amdgcn_mfma_f32_16x16x32_bf16(pa[rt][0], bv0, oacc[rt][dt], 0, 0, 0);
        oacc[rt][dt] = __builtin_amdgcn_mfma_f32_16x16x32_bf16(pa[rt][1], bv1, oacc[rt][dt], 0, 0, 0);
      }
    }
  }
  size_t pbase = (((size_t)(bh * 8 + slice) * M_ + mbase) << 6);
  #pragma unroll
  for (int rt = 0; rt < 2; rt++)
    #pragma unroll
    for (int dt = 0; dt < 4; dt++)
      #pragma unroll
      for (int r = 0; r < 4; r++)
        pvpart[pbase + ((size_t)(rt * 16 + 4 * lg + r) << 6) + dt * 16 + lr] = oacc[rt][dt][r];
  if (lr == 0) {
    #pragma unroll
    for (int rt = 0; rt < 2; rt++)
      #pragma unroll
      for (int r = 0; r < 4; r++)
        msbuf[(size_t)(bh * 8 + slice) * M_ + mbase + rt * 16 + 4 * lg + r] =
            make_float2(mrun[rt * 4 + r], srun[rt * 4 + r]);
  }
}

// ---------------- combine split-N partials -> pv^T bf16 [bh][64][256] ----------------
__global__ __launch_bounds__(256) void pv_combine(const float* __restrict__ pvpart,
    const float2* __restrict__ msbuf, unsigned short* __restrict__ pvT)
{
  int row = blockIdx.x * 4 + (threadIdx.x >> 6);
  int bh = row >> 8, m = row & (M_ - 1);
  int d = threadIdx.x & 63;
  float2 ms[8];
  float mg = -1e30f;
  #pragma unroll
  for (int s = 0; s < 8; s++) {
    ms[s] = msbuf[(size_t)(bh * 8 + s) * M_ + m];
    mg = fmaxf(mg, ms[s].x);
  }
  float ssum = 0.f, o = 0.f;
  #pragma unroll
  for (int s = 0; s < 8; s++) {
    float w = __expf(ms[s].x - mg);
    ssum += ms[s].y * w;
    o += w * pvpart[(((size_t)(bh * 8 + s) * M_ + m) << 6) + d];
  }
  pvT[((size_t)bh << 14) + (size_t)d * M_ + m] = f2bf(o / ssum);
}

// ---------------- attn1: oh = softmax(q @ kl^T) @ W2 via MFMA; kl in LDS, split-m P roundtrip ----------------
__global__ __launch_bounds__(256) void attn1_kernel(
    const unsigned short* __restrict__ qb,
    const unsigned short* __restrict__ klb,
    const unsigned short* __restrict__ w2t,
    unsigned short* __restrict__ oh)
{
  int ntile = blockIdx.x & 31;
  int bh = blockIdx.x >> 5;
  int h = bh & (H_ - 1), b = bh >> 3;
  int tid = threadIdx.x, wid = tid >> 6, lane = tid & 63;
  int lr = lane & 15, lg = lane >> 4;
  __shared__ unsigned short klds[256][68];
  __shared__ unsigned short plds_all[4][16][136];
  unsigned short* plds = &plds_all[wid][0][0];

  const unsigned short* qbh  = qb  + (((size_t)bh * N_) << 6);
  const unsigned short* klbh = klb + ((size_t)bh << 14);
  const unsigned short* w2bh = w2t + ((size_t)bh << 14);

  #pragma unroll
  for (int e = 0; e < 8; e++) {
    int idx = e * 2048 + tid * 8;
    int row = idx >> 6, col = idx & 63;
    *reinterpret_cast<bf16x8*>(&klds[row][col]) =
        *reinterpret_cast<const bf16x8*>(&klbh[((size_t)row << 6) + col]);
  }
  __syncthreads();

  const f32x4 zf = {0.f, 0.f, 0.f, 0.f};
  for (int sub = 0; sub < 4; sub++) {
    int n0 = ntile * 256 + sub * 64 + wid * 16;
    bf16x8 aq0 = *reinterpret_cast<const bf16x8*>(&qbh[((size_t)(n0 + lr) << 6) + lg * 8]);
    bf16x8 aq1 = *reinterpret_cast<const bf16x8*>(&qbh[((size_t)(n0 + lr) << 6) + 32 + lg * 8]);
    f32x4 accs[16];
    __builtin_amdgcn_s_setprio(1);
    #pragma unroll
    for (int mt = 0; mt < 16; mt++) {
      bf16x8 b0 = *reinterpret_cast<const bf16x8*>(&klds[mt * 16 + lr][lg * 8]);
      bf16x8 b1 = *reinterpret_cast<const bf16x8*>(&klds[mt * 16 + lr][32 + lg * 8]);
      f32x4 a = __builtin_amdgcn_mfma_f32_16x16x32_bf16(aq0, b0, zf, 0, 0, 0);
      accs[mt] = __builtin_amdgcn_mfma_f32_16x16x32_bf16(aq1, b1, a, 0, 0, 0);
    }
    __builtin_amdgcn_s_setprio(0);
    float rs[4];
    #pragma unroll
    for (int r = 0; r < 4; r++) {
      float m0 = accs[0][r];
      #pragma unroll
      for (int mt = 1; mt < 16; mt++) m0 = fmaxf(m0, accs[mt][r]);
      #pragma unroll
      for (int off = 1; off < 16; off <<= 1) m0 = fmaxf(m0, __shfl_xor(m0, off));
      float s0 = 0.f;
      #pragma unroll
      for (int mt = 0; mt < 16; mt++) {
        float p = __expf(accs[mt][r] - m0);
        accs[mt][r] = p;
        s0 += p;
      }
      #pragma unroll
      for (int off = 1; off < 16; off <<= 1) s0 += __shfl_xor(s0, off);
      rs[r] = 1.f / s0;
    }
    f32x4 acco[4];
    #pragma unroll
    for (int dt = 0; dt < 4; dt++) acco[dt] = zf;
    #pragma unroll
    for (int half = 0; half < 2; half++) {
      #pragma unroll
      for (int mt = 0; mt < 8; mt++)
        #pragma unroll
        for (int r = 0; r < 4; r++)
          plds[(4 * lg + r) * 136 + mt * 16 + lr] = f2bf(accs[half * 8 + mt][r]);
      __builtin_amdgcn_s_waitcnt(0);
      bf16x8 pa[4];
      #pragma unroll
      for (int mc = 0; mc < 4; mc++)
        pa[mc] = *reinterpret_cast<const bf16x8*>(&plds[lr * 136 + mc * 32 + lg * 8]);
      __builtin_amdgcn_s_setprio(1);
      #pragma unroll
      for (int dt = 0; dt < 4; dt++) {
        #pragma unroll
        for (int mc = 0; mc < 4; mc++) {
          bf16x8 wf = *reinterpret_cast<const bf16x8*>(
              &w2bh[(size_t)(dt * 16 + lr) * M_ + half * 128 + mc * 32 + lg * 8]);
          acco[dt] = __builtin_amdgcn_mfma_f32_16x16x32_bf16(pa[mc], wf, acco[dt], 0, 0, 0);
        }
      }
      __builtin_amdgcn_s_setprio(0);
      __builtin_amdgcn_s_waitcnt(0);
    }
    #pragma unroll
    for (int dt = 0; dt < 4; dt++)
      #pragma unroll
      for (int r = 0; r < 4; r++) {
        int n = n0 + 4 * lg + r;
        oh[((size_t)(b * N_ + n) << 9) + h * DH_ + dt * 16 + lr] = f2bf(acco[dt][r] * rs[r]);
      }
  }
}

// ---------------- depthwise conv residual: register sliding window ----------------
__global__ __launch_bounds__(256) void conv_kernel(const unsigned short* __restrict__ vb,
    const float* __restrict__ rw, unsigned short* __restrict__ oh)
{
  int bh = blockIdx.y;
  int h = bh & (H_ - 1), b = bh >> 3;
  int d = threadIdx.x & 63, g = threadIdx.x >> 6;
  int n0 = blockIdx.x * 128 + g * 32;
  const unsigned short* vbb = vb + (((size_t)bh * N_) << 6) + d;
  float w[64];
  #pragma unroll
  for (int j = 0; j < 64; j++) {
    int nn = n0 - 16 + j;
    w[j] = (nn >= 0 && nn < N_) ? bf2f(vbb[(size_t)nn << 6]) : 0.f;
  }
  float rwr[RESK_];
  #pragma unroll
  for (int j = 0; j < RESK_; j++) rwr[j] = rw[h * RESK_ + j];
  size_t obase = (((size_t)(b * N_ + n0)) << 9) + h * 64 + d;
  #pragma unroll
  for (int t = 0; t < 32; t++) {
    float acc = 0.f;
    #pragma unroll
    for (int j = 0; j < RESK_; j++) acc += rwr[j] * w[t + j];
    size_t oi = obase + ((size_t)t << 9);
    oh[oi] = f2bf(bf2f(oh[oi]) + acc);
  }
}

extern "C" void kernel_launch(void* const* d_in, const int* in_sizes, int n_in,
                              void* d_out, int out_size, void* d_ws, size_t ws_size,
                              hipStream_t stream)
{
  const float* x     = (const float*)d_in[0];
  const float* ln_w  = (const float*)d_in[1];
  const float* ln_b  = (const float*)d_in[2];
  const float* w_qkv = (const float*)d_in[3];
  const float* w_out = (const float*)d_in[4];
  const float* b_out = (const float*)d_in[5];
  const float* res_w = (const float*)d_in[6];
  float* out = (float*)d_out;

  const size_t HEADEL = (size_t)B_ * H_ * N_ * DH_;
  const size_t SMALL  = (size_t)B_ * H_ * M_ * DH_;
  const size_t MSQ    = (size_t)B_ * H_ * M_ * M_;

  char* p = (char*)d_ws;
  auto alloc = [&](size_t bytes) { char* r = p; p += (bytes + 255) & ~(size_t)255; return r; };

  unsigned short* qb  = (unsigned short*)alloc(HEADEL * 2);
  unsigned short* kb  = (unsigned short*)alloc(HEADEL * 2);
  unsigned short* vb  = (unsigned short*)alloc(HEADEL * 2);
  unsigned short* oh  = (unsigned short*)alloc(HEADEL * 2);
  char* unA = alloc(HEADEL * 2);
  unsigned short* xnb = (unsigned short*)unA;
  unsigned short* z0R = (unsigned short*)unA;
  unsigned short* z0T = z0R + MSQ;
  unsigned short* z1R = z0T + MSQ;
  unsigned short* u2  = z1R + MSQ;
  char* unB = alloc(HEADEL * 2);
  float*  pvpart = (float*)unB;
  float2* msbuf  = (float2*)(unB + (size_t)B_ * H_ * 8 * M_ * DH_ * 4);
  unsigned short* ub  = (unsigned short*)unB;
  unsigned short* vTb = ub + MSQ;
  unsigned short* wTb = vTb + MSQ;
  unsigned short* yTb = wTb + MSQ;

  unsigned short* wqkvT = (unsigned short*)alloc((size_t)K3_ * DIM_ * 2);
  unsigned short* woutT = (unsigned short*)alloc((size_t)DIM_ * INNER_ * 2);
  float* ql  = (float*)alloc(SMALL * 4);
  float* kl  = (float*)alloc(SMALL * 4);
  unsigned short* qlb = (unsigned short*)alloc(SMALL * 2);
  unsigned short* klb = (unsigned short*)alloc(SMALL * 2);
  unsigned short* pvT = (unsigned short*)alloc(SMALL * 2);
  unsigned short* w2t = (unsigned short*)alloc(SMALL * 2);
  unsigned short* a2b = (unsigned short*)alloc(MSQ * 2);
  unsigned int* scal  = (unsigned int*)alloc(256);
  if ((size_t)(p - (char*)d_ws) > ws_size) return;

  float* a2 = (float*)d_out;

  ln_bf16<<<B_ * N_, 256, 0, stream>>>(x, ln_w, ln_b, xnb);
  transpose_w<<<dim3(K3_ / 64, DIM_ / 64), 256, 0, stream>>>(w_qkv, wqkvT, DIM_, K3_, INNER_, 0.125f);
  transpose_w<<<dim3(DIM_ / 64, INNER_ / 64), 256, 0, stream>>>(w_out, woutT, INNER_, DIM_, 0, 1.f);
  mfma_qkv<<<dim3(K3_ / 128, (B_ * N_) / 128), 256, 0, stream>>>(xnb, wqkvT, qb, kb, vb);
  landmark_kernel<<<B_ * H_ * M_, 64, 0, stream>>>(qb, kb, ql, kl, qlb, klb);
  attn2_kernel<<<B_ * H_ * M_, 256, 0, stream>>>(ql, kl, a2, a2b);
  zero_scal<<<1, 2, 0, stream>>>(scal);
  pinv_scale_kernel<<<B_ * H_, 256, 0, stream>>>(a2, scal);
  pv_mfma<<<dim3(8, 1, B_ * H_), 512, 0, stream>>>(kb, vb, qlb, pvpart, msbuf);
  pv_combine<<<(B_ * H_ * M_) / 4, 256, 0, stream>>>(pvpart, msbuf, pvT);
  zinit_kernel<<<dim3(4, 4, B_ * H_), 256, 0, stream>>>(a2, scal, z0R, z0T);

  dim3 g44(4, 4, B_ * H_);
  dim3 g48(4, 8, B_ * H_);
  bgemm_ns<<<g44, 512, 0, stream>>>(a2b, z0T, ub, vTb, 7.f, -1.f, 1.f);
  unsigned short *cR = z0R, *nR = z1R, *cu = ub, *nu = u2;
  for (int it = 0; it < 6; it++) {
    bgemm_ns<<<g44, 512, 0, stream>>>(cu, vTb, nullptr, wTb, 15.f, -1.f, 0.f);
    bgemm_ns<<<g44, 512, 0, stream>>>(cu, wTb, nullptr, yTb, 13.f, -1.f, 0.f);
    if (it < 5) {
      bgemm_ns2<<<g48, 512, 0, stream>>>(cR, cu, yTb, nR, nu, vTb, 4);
      unsigned short* t;
      t = cR; cR = nR; nR = t;  t = cu; cu = nu; nu = t;
    } else {
      bgemm_ns2<<<g44, 512, 0, stream>>>(cR, cu, yTb, nR, nu, vTb, 4);
      cR = nR;
    }
  }

  gemm_w2<<<dim3(4, B_ * H_), 256, 0, stream>>>(cR, pvT, w2t);

  attn1_kernel<<<B_ * H_ * (N_ / 256), 256, 0, stream>>>(qb, klb, w2t, oh);
  conv_kernel<<<dim3(N_ / 128, B_ * H_), 256, 0, stream>>>(vb, res_w, oh);
  mfma_out<<<dim3(DIM_ / 128, (B_ * N_) / 128), 256, 0, stream>>>(oh, woutT, b_out, x, out);
}